// Round 11
// baseline (347.984 us; speedup 1.0000x reference)
//
#include <hip/hip_runtime.h>
#include <stdint.h>

typedef float f32x4 __attribute__((ext_vector_type(4)));
typedef __bf16 bf16x8 __attribute__((ext_vector_type(8)));
typedef uint32_t u32a  __attribute__((may_alias));
typedef uint2    u2a   __attribute__((may_alias));
typedef uint4    u4a   __attribute__((may_alias));

#define VS 2064   // Vt row stride in elements (2048 + 16: breaks 4KB L2 aliasing)
#define GS 68     // GEMM LDS row stride (64 + 4: 2-way-max bank spread)

__device__ __forceinline__ ushort f2b(float f) {
  uint32_t u = __builtin_bit_cast(uint32_t, f);
  u += 0x7FFFu + ((u >> 16) & 1u);   // round-to-nearest-even
  return (ushort)(u >> 16);
}
__device__ __forceinline__ uint32_t b16(uint32_t u) {  // fp32 bits -> bf16 bits (RNE)
  u += 0x7FFFu + ((u >> 16) & 1u);
  return u >> 16;
}

__device__ __forceinline__ bf16x8 ld_frag(const ushort* p) {
  u4a u = *(const u4a*)p;            // ds_read_b128 / global_load_dwordx4
  return __builtin_bit_cast(bf16x8, u);
}

// 8 fp32 -> 8 bf16 packed (two dwordx4 loads + RNE pack)
__device__ __forceinline__ u4a cvt8(const float* p) {
  u4a a = *(const u4a*)p, b = *(const u4a*)(p + 4), o;
  o.x = b16(a.x) | (b16(a.y) << 16);
  o.y = b16(a.z) | (b16(a.w) << 16);
  o.z = b16(b.x) | (b16(b.y) << 16);
  o.w = b16(b.z) | (b16(b.w) << 16);
  return o;
}

// combine two packed bf16 pairs with weights w0,w1, repack
__device__ __forceinline__ uint32_t comb2(uint32_t a, uint32_t b, float w0, float w1) {
  float lo = __builtin_bit_cast(float, a << 16) * w0 +
             __builtin_bit_cast(float, b << 16) * w1;
  float hi = __builtin_bit_cast(float, a & 0xFFFF0000u) * w0 +
             __builtin_bit_cast(float, b & 0xFFFF0000u) * w1;
  return (uint32_t)f2b(lo) | ((uint32_t)f2b(hi) << 16);
}

// ---------------------------------------------------------------------------
// fp32 -> bf16 one-shot convert: x (3145728) then wq/wk/wv/wo (589824 each).
// ---------------------------------------------------------------------------
__global__ __launch_bounds__(256) void convert_kernel(
    const float* __restrict__ x,  const float* __restrict__ wq,
    const float* __restrict__ wk, const float* __restrict__ wv,
    const float* __restrict__ wo,
    ushort* __restrict__ xb,  ushort* __restrict__ wqb,
    ushort* __restrict__ wkb, ushort* __restrict__ wvb,
    ushort* __restrict__ wob)
{
  const size_t NX = 3145728, NW = 589824;
  size_t idx = ((size_t)blockIdx.x * 256 + threadIdx.x) * 8;
  const float* src; ushort* dst; size_t off;
  if      (idx < NX)          { src = x;  dst = xb;  off = idx; }
  else if (idx < NX + NW)     { src = wq; dst = wqb; off = idx - NX; }
  else if (idx < NX + 2 * NW) { src = wk; dst = wkb; off = idx - NX - NW; }
  else if (idx < NX + 3 * NW) { src = wv; dst = wvb; off = idx - NX - 2 * NW; }
  else                        { src = wo; dst = wob; off = idx - NX - 3 * NW; }
  *(u4a*)(dst + off) = cvt8(src + off);
}

// ---------------------------------------------------------------------------
// QKV: C[M,N]=A[M,K]*B[N,K]^T, bf16, fp32 acc. BM=128 BN=64 BK=64, 256 thr.
// Register-double-buffered staging: fetch tile k+1 into VGPRs while MFMAs
// consume tile k from LDS. grid (32,12,3). z: 0->Q (PRE-SCALED 1/8),
// 1->K row-major; 2->V transposed to Vt[b][h][dv][s] (stride VS).
// ---------------------------------------------------------------------------
__global__ __launch_bounds__(256) void gemm_qkv(
    const ushort* __restrict__ A,
    const ushort* __restrict__ B0, const ushort* __restrict__ B1,
    const ushort* __restrict__ B2,
    ushort* __restrict__ Qo, ushort* __restrict__ Ko, ushort* __restrict__ Vt,
    int M, int N, int K)
{
  const ushort* B = blockIdx.z == 0 ? B0 : (blockIdx.z == 1 ? B1 : B2);
  const int m0 = blockIdx.x * 128, n0 = blockIdx.y * 64;
  __shared__ ushort As[128 * GS];   // [128][64] padded
  __shared__ ushort Bs[64 * GS];
  const int tid = threadIdx.x, wave = tid >> 6, lane = tid & 63;
  const int quad = lane >> 4, l16 = lane & 15;
  const int mw = (wave & 1) * 64, nw = (wave >> 1) * 32;
  f32x4 acc[4][2] = {};

  u4a pa[4], pb[2];
  auto fetch = [&](int k0) {
#pragma unroll
    for (int i = 0; i < 4; ++i) {
      int c = i * 256 + tid;
      pa[i] = *(const u4a*)(A + (size_t)(m0 + (c >> 3)) * K + k0 + (c & 7) * 8);
    }
#pragma unroll
    for (int i = 0; i < 2; ++i) {
      int c = i * 256 + tid;
      pb[i] = *(const u4a*)(B + (size_t)(n0 + (c >> 3)) * K + k0 + (c & 7) * 8);
    }
  };
  fetch(0);

  for (int k0 = 0; k0 < K; k0 += 64) {
    // drain prefetched regs into LDS
#pragma unroll
    for (int i = 0; i < 4; ++i) {
      int c = i * 256 + tid;
      *(u4a*)(As + (c >> 3) * GS + (c & 7) * 8) = pa[i];
    }
#pragma unroll
    for (int i = 0; i < 2; ++i) {
      int c = i * 256 + tid;
      *(u4a*)(Bs + (c >> 3) * GS + (c & 7) * 8) = pb[i];
    }
    __syncthreads();
    if (k0 + 64 < K) fetch(k0 + 64);   // latency overlaps the MFMAs below
#pragma unroll
    for (int ks = 0; ks < 2; ++ks) {
      bf16x8 af[4], bfr[2];
#pragma unroll
      for (int i = 0; i < 4; ++i)
        af[i]  = ld_frag(As + (mw + i * 16 + l16) * GS + ks * 32 + quad * 8);
#pragma unroll
      for (int j = 0; j < 2; ++j)
        bfr[j] = ld_frag(Bs + (nw + j * 16 + l16) * GS + ks * 32 + quad * 8);
#pragma unroll
      for (int i = 0; i < 4; ++i)
#pragma unroll
        for (int j = 0; j < 2; ++j)
          acc[i][j] = __builtin_amdgcn_mfma_f32_16x16x32_bf16(af[i], bfr[j], acc[i][j], 0, 0, 0);
    }
    __syncthreads();
  }
  // C/D layout: col=lane&15 (N), row=quad*4+reg (M)
  if (blockIdx.z < 2) {
    ushort* C = blockIdx.z == 0 ? Qo : Ko;
    const float sc = blockIdx.z == 0 ? 0.125f : 1.0f;  // fold 1/sqrt(dk) into Q
#pragma unroll
    for (int i = 0; i < 4; ++i)
#pragma unroll
      for (int j = 0; j < 2; ++j)
#pragma unroll
        for (int r = 0; r < 4; ++r) {
          int row = m0 + mw + i * 16 + quad * 4 + r;
          int col = n0 + nw + j * 16 + l16;
          C[(size_t)row * N + col] = f2b(acc[i][j][r] * sc);
        }
  } else {
    // Vt[b][h][dv][s] (stride VS): h == blockIdx.y, dv = col&63
#pragma unroll
    for (int i = 0; i < 4; ++i)
#pragma unroll
      for (int j = 0; j < 2; ++j) {
        int col = n0 + nw + j * 16 + l16;
        int h = col >> 6, dv = col & 63;
        int t = m0 + mw + i * 16 + quad * 4;
        int b = t >> 11, s = t & 2047;
        u2a pw;
        pw.x = (uint32_t)f2b(acc[i][j][0]) | ((uint32_t)f2b(acc[i][j][1]) << 16);
        pw.y = (uint32_t)f2b(acc[i][j][2]) | ((uint32_t)f2b(acc[i][j][3]) << 16);
        *(u2a*)(Vt + (((size_t)b * 12 + h) * 64 + dv) * VS + s) = pw;
      }
  }
}

// ---------------------------------------------------------------------------
// Output projection: C[M,N](fp32) = A[M,K](bf16)*B[N,K]^T(bf16).
// BM=BN=64, BK=64, register-double-buffered. grid (64,12) = 768 blocks.
// ---------------------------------------------------------------------------
__global__ __launch_bounds__(256) void gemm_out(
    const ushort* __restrict__ A, const ushort* __restrict__ B,
    float* __restrict__ C, int M, int N, int K)
{
  const int m0 = blockIdx.x * 64, n0 = blockIdx.y * 64;
  __shared__ ushort As[64 * GS];
  __shared__ ushort Bs[64 * GS];
  const int tid = threadIdx.x, wave = tid >> 6, lane = tid & 63;
  const int quad = lane >> 4, l16 = lane & 15;
  const int mw = (wave & 1) * 32, nw = (wave >> 1) * 32;
  f32x4 acc[2][2] = {};

  u4a pa[2], pb[2];
  auto fetch = [&](int k0) {
#pragma unroll
    for (int i = 0; i < 2; ++i) {
      int c = i * 256 + tid;
      pa[i] = *(const u4a*)(A + (size_t)(m0 + (c >> 3)) * K + k0 + (c & 7) * 8);
      pb[i] = *(const u4a*)(B + (size_t)(n0 + (c >> 3)) * K + k0 + (c & 7) * 8);
    }
  };
  fetch(0);

  for (int k0 = 0; k0 < K; k0 += 64) {
#pragma unroll
    for (int i = 0; i < 2; ++i) {
      int c = i * 256 + tid;
      *(u4a*)(As + (c >> 3) * GS + (c & 7) * 8) = pa[i];
      *(u4a*)(Bs + (c >> 3) * GS + (c & 7) * 8) = pb[i];
    }
    __syncthreads();
    if (k0 + 64 < K) fetch(k0 + 64);
#pragma unroll
    for (int ks = 0; ks < 2; ++ks) {
      bf16x8 af[2], bfr[2];
#pragma unroll
      for (int i = 0; i < 2; ++i)
        af[i]  = ld_frag(As + (mw + i * 16 + l16) * GS + ks * 32 + quad * 8);
#pragma unroll
      for (int j = 0; j < 2; ++j)
        bfr[j] = ld_frag(Bs + (nw + j * 16 + l16) * GS + ks * 32 + quad * 8);
#pragma unroll
      for (int i = 0; i < 2; ++i)
#pragma unroll
        for (int j = 0; j < 2; ++j)
          acc[i][j] = __builtin_amdgcn_mfma_f32_16x16x32_bf16(af[i], bfr[j], acc[i][j], 0, 0, 0);
    }
    __syncthreads();
  }
#pragma unroll
  for (int i = 0; i < 2; ++i)
#pragma unroll
    for (int j = 0; j < 2; ++j)
#pragma unroll
      for (int r = 0; r < 4; ++r) {
        int row = m0 + mw + i * 16 + quad * 4 + r;
        int col = n0 + nw + j * 16 + l16;
        C[(size_t)row * N + col] = acc[i][j][r];
      }
}

// ---------------------------------------------------------------------------
// Causal flash attention, TILE-SHARED strips + K-split + register-prefetched
// staging: grid (32,12,2); x = pair*2 + j. Block owns q-tiles A=pair, B=31-pair;
// iterates kt ≡ j (mod 2) to nktB, staging each K/V tile once for both strips.
// Next tile is fetched into VGPRs while the current tile is computed.
// Q pre-scaled by 1/8. Emits unnormalized partials + (m,l) per strip.
// ---------------------------------------------------------------------------
__global__ __launch_bounds__(256) void attn_kernel(
    const ushort* __restrict__ Qb, const ushort* __restrict__ Kb,
    const ushort* __restrict__ Vt, ushort* __restrict__ Opart,
    float2* __restrict__ MLp)
{
  const int S = 2048, DM = 768;
  const int pair = blockIdx.x >> 1, j = blockIdx.x & 1;
  const int h = blockIdx.y, bb = blockIdx.z;
  const ushort* Qp  = Qb + (size_t)bb * S * DM + h * 64;
  const ushort* Kp  = Kb + (size_t)bb * S * DM + h * 64;
  const ushort* Vth = Vt + ((size_t)bb * 12 + h) * 64 * VS;   // [dv][s]

  __shared__ ushort Ks[128 * 72];     // [kk][dk], pad 64->72
  __shared__ ushort Vs[64 * 136];     // [dv][kk], pad 128->136
  __shared__ ushort Ps[4][16 * 136];  // per-wave P[q][kk], pad 128->136

  const int tid = threadIdx.x, wave = tid >> 6, lane = tid & 63;
  const int quad = lane >> 4, l16 = lane & 15;
  const float LOG2E = 1.44269504f;
  const float NEG_BIG = -1.0e30f;

  const int qtA = pair, qtB = 31 - pair;
  const int qgA = qtA * 64 + wave * 16 + l16;
  const int qgB = qtB * 64 + wave * 16 + l16;
  const int nktA = (qtA >> 1) + 1, nktB = (qtB >> 1) + 1;

  // Q fragments for both strips (B operand of S^T = K*Q^T)
  bf16x8 bqA0 = ld_frag(Qp + (size_t)qgA * DM + quad * 8);
  bf16x8 bqA1 = ld_frag(Qp + (size_t)qgA * DM + 32 + quad * 8);
  bf16x8 bqB0 = ld_frag(Qp + (size_t)qgB * DM + quad * 8);
  bf16x8 bqB1 = ld_frag(Qp + (size_t)qgB * DM + 32 + quad * 8);

  f32x4 accA[4] = {}, accB[4] = {};
  float mA = NEG_BIG, lA = 0.0f, mB = NEG_BIG, lB = 0.0f;

  u4a kr[4], vr[4];
  auto fetch_tile = [&](int kt) {
    const int kk0 = kt * 128;
#pragma unroll
    for (int i = 0; i < 4; ++i) {
      int c = i * 256 + tid;
      kr[i] = *(const u4a*)(Kp + (size_t)(kk0 + (c >> 3)) * DM + (c & 7) * 8);
      vr[i] = *(const u4a*)(Vth + (size_t)(c >> 4) * VS + kk0 + (c & 15) * 8);
    }
  };
  fetch_tile(j);

  for (int kt = j; kt < nktB; kt += 2) {
    const int kk0 = kt * 128;
    // drain prefetched regs into LDS
#pragma unroll
    for (int i = 0; i < 4; ++i) {
      int c = i * 256 + tid;
      *(u4a*)(Ks + (c >> 3) * 72 + (c & 7) * 8) = kr[i];
      *(u4a*)(Vs + (c >> 4) * 136 + (c & 15) * 8) = vr[i];
    }
    __syncthreads();
    if (kt + 2 < nktB) fetch_tile(kt + 2);   // latency overlaps compute below

    // ---- compute one strip from the staged tile ----
    auto strip = [&](const bf16x8& bq0, const bf16x8& bq1, f32x4* acc_o,
                     float& m_run, float& l_run, int qg, int nkt) {
      f32x4 sacc[8] = {};
#pragma unroll
      for (int tt = 0; tt < 8; ++tt) {
        bf16x8 ak0 = ld_frag(Ks + (tt * 16 + l16) * 72 + quad * 8);
        bf16x8 ak1 = ld_frag(Ks + (tt * 16 + l16) * 72 + 32 + quad * 8);
        sacc[tt] = __builtin_amdgcn_mfma_f32_16x16x32_bf16(ak0, bq0, sacc[tt], 0, 0, 0);
        sacc[tt] = __builtin_amdgcn_mfma_f32_16x16x32_bf16(ak1, bq1, sacc[tt], 0, 0, 0);
      }
      const bool domask = (kt == nkt - 1);
      float mt = NEG_BIG;
#pragma unroll
      for (int tt = 0; tt < 8; ++tt)
#pragma unroll
        for (int r = 0; r < 4; ++r) {
          float s = sacc[tt][r];
          if (domask) {
            int kkg = kk0 + tt * 16 + quad * 4 + r;
            if (kkg > qg) s = NEG_BIG;
          }
          sacc[tt][r] = s;
          mt = fmaxf(mt, s);
        }
      mt = fmaxf(mt, __shfl_xor(mt, 16, 64));
      mt = fmaxf(mt, __shfl_xor(mt, 32, 64));
      float mnew = fmaxf(m_run, mt);
      float alpha = exp2f((m_run - mnew) * LOG2E);
      float lsum = 0.0f;
#pragma unroll
      for (int tt = 0; tt < 8; ++tt) {
        float p0 = exp2f((sacc[tt][0] - mnew) * LOG2E);
        float p1 = exp2f((sacc[tt][1] - mnew) * LOG2E);
        float p2 = exp2f((sacc[tt][2] - mnew) * LOG2E);
        float p3 = exp2f((sacc[tt][3] - mnew) * LOG2E);
        lsum += (p0 + p1) + (p2 + p3);
        // truncation pack (P in [0,1]: <=2^-8 rel err)
        uint32_t u0 = __builtin_bit_cast(uint32_t, p0);
        uint32_t u1 = __builtin_bit_cast(uint32_t, p1);
        uint32_t u2 = __builtin_bit_cast(uint32_t, p2);
        uint32_t u3 = __builtin_bit_cast(uint32_t, p3);
        u2a pw;
        pw.x = (u0 >> 16) | (u1 & 0xFFFF0000u);
        pw.y = (u2 >> 16) | (u3 & 0xFFFF0000u);
        *(u2a*)(&Ps[wave][l16 * 136 + tt * 16 + quad * 4]) = pw;
      }
      asm volatile("s_waitcnt lgkmcnt(0)" ::: "memory");
      lsum += __shfl_xor(lsum, 16, 64);
      lsum += __shfl_xor(lsum, 32, 64);
      l_run = l_run * alpha + lsum;
      m_run = mnew;
      float ar0 = __shfl(alpha, quad * 4 + 0, 64);
      float ar1 = __shfl(alpha, quad * 4 + 1, 64);
      float ar2 = __shfl(alpha, quad * 4 + 2, 64);
      float ar3 = __shfl(alpha, quad * 4 + 3, 64);
#pragma unroll
      for (int ct = 0; ct < 4; ++ct) {
        acc_o[ct][0] *= ar0; acc_o[ct][1] *= ar1;
        acc_o[ct][2] *= ar2; acc_o[ct][3] *= ar3;
      }
#pragma unroll
      for (int ks = 0; ks < 4; ++ks) {
        bf16x8 ap = ld_frag(&Ps[wave][l16 * 136 + ks * 32 + quad * 8]);
#pragma unroll
        for (int ct = 0; ct < 4; ++ct) {
          bf16x8 bv = ld_frag(Vs + (size_t)(ct * 16 + l16) * 136 + ks * 32 + quad * 8);
          acc_o[ct] = __builtin_amdgcn_mfma_f32_16x16x32_bf16(ap, bv, acc_o[ct], 0, 0, 0);
        }
      }
    };

    strip(bqB0, bqB1, accB, mB, lB, qgB, nktB);       // always active
    if (kt < nktA)
      strip(bqA0, bqA1, accA, mA, lA, qgA, nktA);     // block-uniform branch
    __syncthreads();   // protect Ks/Vs before next restage
  }

  // store unnormalized partials (bf16 O + per-row m,l) for both strips
  const int base = ((bb * 12 + h) << 5);
  const int r0 = wave * 16 + quad * 4;
  {
    const int slot = (base + qtB) * 2 + j;
    ushort* Os = Opart + (size_t)slot * 4096;
#pragma unroll
    for (int ct = 0; ct < 4; ++ct) {
      int col = ct * 16 + l16;
      Os[(r0 + 0) * 64 + col] = f2b(accB[ct][0]);
      Os[(r0 + 1) * 64 + col] = f2b(accB[ct][1]);
      Os[(r0 + 2) * 64 + col] = f2b(accB[ct][2]);
      Os[(r0 + 3) * 64 + col] = f2b(accB[ct][3]);
    }
    if (quad == 0)
      MLp[(size_t)slot * 64 + wave * 16 + l16] = make_float2(mB, lB);
  }
  {
    const int slot = (base + qtA) * 2 + j;
    ushort* Os = Opart + (size_t)slot * 4096;
#pragma unroll
    for (int ct = 0; ct < 4; ++ct) {
      int col = ct * 16 + l16;
      Os[(r0 + 0) * 64 + col] = f2b(accA[ct][0]);
      Os[(r0 + 1) * 64 + col] = f2b(accA[ct][1]);
      Os[(r0 + 2) * 64 + col] = f2b(accA[ct][2]);
      Os[(r0 + 3) * 64 + col] = f2b(accA[ct][3]);
    }
    if (quad == 0)
      MLp[(size_t)slot * 64 + wave * 16 + l16] = make_float2(mA, lA);
  }
}

// ---------------------------------------------------------------------------
// Combine the two K-parity partials per strip -> Abuf (b, s, h*64) bf16.
// grid 768, 256 threads, 16 elems/thread. Empty partial: m=-1e30 -> weight 0.
// ---------------------------------------------------------------------------
__global__ __launch_bounds__(256) void combine_kernel(
    const ushort* __restrict__ Opart, const float2* __restrict__ MLp,
    ushort* __restrict__ Ab)
{
  const int sid = blockIdx.x;
  const int bb = sid / 384, rem = sid % 384, h = rem >> 5, qt = rem & 31;
  const int t = threadIdx.x, row = t >> 2, cg = (t & 3) * 16;
  float2 ml0 = MLp[(size_t)(sid * 2) * 64 + row];
  float2 ml1 = MLp[(size_t)(sid * 2 + 1) * 64 + row];
  float ms = fmaxf(ml0.x, ml1.x);
  float w0 = exp2f((ml0.x - ms) * 1.44269504f);
  float w1 = exp2f((ml1.x - ms) * 1.44269504f);
  float inv = 1.0f / (ml0.y * w0 + ml1.y * w1);
  w0 *= inv; w1 *= inv;
  const ushort* p0 = Opart + (size_t)(sid * 2) * 4096 + row * 64 + cg;
  ushort* dst = Ab + ((size_t)(bb * 2048 + qt * 64 + row)) * 768 + h * 64 + cg;
#pragma unroll
  for (int g = 0; g < 2; ++g) {
    u4a a = *(const u4a*)(p0 + g * 8);
    u4a b = *(const u4a*)(p0 + 4096 + g * 8);
    u4a o;
    o.x = comb2(a.x, b.x, w0, w1);
    o.y = comb2(a.y, b.y, w0, w1);
    o.z = comb2(a.z, b.z, w0, w1);
    o.w = comb2(a.w, b.w, w0, w1);
    *(u4a*)(dst + g * 8) = o;
  }
}

// ---------------------------------------------------------------------------
extern "C" void kernel_launch(void* const* d_in, const int* in_sizes, int n_in,
                              void* d_out, int out_size, void* d_ws, size_t ws_size,
                              hipStream_t stream) {
  (void)in_sizes; (void)n_in; (void)out_size; (void)ws_size;
  const float* x  = (const float*)d_in[0];
  const float* wq = (const float*)d_in[1];
  const float* wk = (const float*)d_in[2];
  const float* wv = (const float*)d_in[3];
  const float* wo = (const float*)d_in[4];

  const size_t NT = (size_t)4096 * 768;   // tokens x d_model
  const size_t NW = (size_t)768 * 768;
  const size_t NV = (size_t)24 * 64 * VS; // padded Vt
  ushort* xb    = (ushort*)d_ws;          // reused as Abuf after QKV GEMM
  ushort* Qbuf  = xb + NT;
  ushort* Kbuf  = Qbuf + NT;
  ushort* Vt    = Kbuf + NT;              // (b, h, dv, s) stride VS
  ushort* wqb   = Vt + NV;
  ushort* wkb   = wqb + NW;
  ushort* wvb   = wkb + NW;
  ushort* wob   = wvb + NW;
  ushort* Opart = wob + NW;               // 1536 x 64 x 64 bf16
  float2* MLp   = (float2*)(Opart + (size_t)1536 * 4096);  // 1536 x 64
  ushort* Abuf  = xb;                     // lifetime-disjoint reuse

  // fp32 -> bf16 (x + all weights)
  convert_kernel<<<2688, 256, 0, stream>>>(x, wq, wk, wv, wo,
                                           xb, wqb, wkb, wvb, wob);
  // Q/K/V projections (Q pre-scaled; V lands transposed in Vt)
  gemm_qkv<<<dim3(32, 12, 3), 256, 0, stream>>>(
      xb, wqb, wkb, wvb, Qbuf, Kbuf, Vt, 4096, 768, 768);
  // causal flash attention: shared-tile strips, 768 uniform sub-blocks
  attn_kernel<<<dim3(32, 12, 2), 256, 0, stream>>>(Qbuf, Kbuf, Vt, Opart, MLp);
  // merge partials -> Abuf
  combine_kernel<<<768, 256, 0, stream>>>(Opart, MLp, Abuf);
  // output projection (fp32 out)
  gemm_out<<<dim3(64, 12), 256, 0, stream>>>(
      Abuf, wob, (float*)d_out, 4096, 768, 768);
}

// Round 12
// 278.746 us; speedup vs baseline: 1.2484x; 1.2484x over previous
//
#include <hip/hip_runtime.h>
#include <stdint.h>

typedef float f32x4 __attribute__((ext_vector_type(4)));
typedef __bf16 bf16x8 __attribute__((ext_vector_type(8)));
typedef uint32_t u32a  __attribute__((may_alias));
typedef uint2    u2a   __attribute__((may_alias));
typedef uint4    u4a   __attribute__((may_alias));

#define VS 2064   // Vt row stride in elements (2048 + 16: breaks 4KB L2 aliasing)
#define GS 68     // GEMM LDS row stride (64 + 4) -> zero bank conflicts (R11 PMC)

__device__ __forceinline__ ushort f2b(float f) {
  uint32_t u = __builtin_bit_cast(uint32_t, f);
  u += 0x7FFFu + ((u >> 16) & 1u);   // round-to-nearest-even
  return (ushort)(u >> 16);
}
__device__ __forceinline__ uint32_t b16(uint32_t u) {  // fp32 bits -> bf16 bits (RNE)
  u += 0x7FFFu + ((u >> 16) & 1u);
  return u >> 16;
}

__device__ __forceinline__ bf16x8 ld_frag(const ushort* p) {
  u4a u = *(const u4a*)p;            // ds_read_b128 / global_load_dwordx4
  return __builtin_bit_cast(bf16x8, u);
}

// 8 fp32 -> 8 bf16 packed (two dwordx4 loads + RNE pack)
__device__ __forceinline__ u4a cvt8(const float* p) {
  u4a a = *(const u4a*)p, b = *(const u4a*)(p + 4), o;
  o.x = b16(a.x) | (b16(a.y) << 16);
  o.y = b16(a.z) | (b16(a.w) << 16);
  o.z = b16(b.x) | (b16(b.y) << 16);
  o.w = b16(b.z) | (b16(b.w) << 16);
  return o;
}

// combine two packed bf16 pairs with weights w0,w1, repack
__device__ __forceinline__ uint32_t comb2(uint32_t a, uint32_t b, float w0, float w1) {
  float lo = __builtin_bit_cast(float, a << 16) * w0 +
             __builtin_bit_cast(float, b << 16) * w1;
  float hi = __builtin_bit_cast(float, a & 0xFFFF0000u) * w0 +
             __builtin_bit_cast(float, b & 0xFFFF0000u) * w1;
  return (uint32_t)f2b(lo) | ((uint32_t)f2b(hi) << 16);
}

// ---------------------------------------------------------------------------
// fp32 -> bf16 one-shot convert: x (3145728) then wq/wk/wv/wo (589824 each).
// ---------------------------------------------------------------------------
__global__ __launch_bounds__(256) void convert_kernel(
    const float* __restrict__ x,  const float* __restrict__ wq,
    const float* __restrict__ wk, const float* __restrict__ wv,
    const float* __restrict__ wo,
    ushort* __restrict__ xb,  ushort* __restrict__ wqb,
    ushort* __restrict__ wkb, ushort* __restrict__ wvb,
    ushort* __restrict__ wob)
{
  const size_t NX = 3145728, NW = 589824;
  size_t idx = ((size_t)blockIdx.x * 256 + threadIdx.x) * 8;
  const float* src; ushort* dst; size_t off;
  if      (idx < NX)          { src = x;  dst = xb;  off = idx; }
  else if (idx < NX + NW)     { src = wq; dst = wqb; off = idx - NX; }
  else if (idx < NX + 2 * NW) { src = wk; dst = wkb; off = idx - NX - NW; }
  else if (idx < NX + 3 * NW) { src = wv; dst = wvb; off = idx - NX - 2 * NW; }
  else                        { src = wo; dst = wob; off = idx - NX - 3 * NW; }
  *(u4a*)(dst + off) = cvt8(src + off);
}

// ---------------------------------------------------------------------------
// QKV: C[M,N]=A[M,K]*B[N,K]^T, bf16, fp32 acc. BM=128 BN=64 BK=64, 256 thr.
// Register double-buffer with NAMED scalars (no arrays/lambda -> no spill).
// grid (32,12,3). z: 0->Q (PRE-SCALED 1/8), 1->K; 2->V transposed to Vt.
// ---------------------------------------------------------------------------
__global__ __launch_bounds__(256) void gemm_qkv(
    const ushort* __restrict__ A,
    const ushort* __restrict__ B0, const ushort* __restrict__ B1,
    const ushort* __restrict__ B2,
    ushort* __restrict__ Qo, ushort* __restrict__ Ko, ushort* __restrict__ Vt,
    int M, int N, int K)
{
  const ushort* B = blockIdx.z == 0 ? B0 : (blockIdx.z == 1 ? B1 : B2);
  const int m0 = blockIdx.x * 128, n0 = blockIdx.y * 64;
  __shared__ ushort As[128 * GS];
  __shared__ ushort Bs[64 * GS];
  const int tid = threadIdx.x, wave = tid >> 6, lane = tid & 63;
  const int quad = lane >> 4, l16 = lane & 15;
  const int mw = (wave & 1) * 64, nw = (wave >> 1) * 32;
  const int rr = tid >> 3, cc = (tid & 7) * 8;   // my chunk row/col
  const ushort* Ag = A + (size_t)(m0 + rr) * K + cc;
  const ushort* Bg = B + (size_t)(n0 + rr) * K + cc;
  const size_t a32 = (size_t)32 * K;
  ushort* Al = As + rr * GS + cc;
  ushort* Bl = Bs + rr * GS + cc;
  f32x4 acc[4][2] = {};

  u4a pa0, pa1, pa2, pa3, pb0, pb1;
#define QKV_FETCH(k0_)                                   \
  pa0 = *(const u4a*)(Ag + (k0_));                       \
  pa1 = *(const u4a*)(Ag + (k0_) + a32);                 \
  pa2 = *(const u4a*)(Ag + (k0_) + 2 * a32);             \
  pa3 = *(const u4a*)(Ag + (k0_) + 3 * a32);             \
  pb0 = *(const u4a*)(Bg + (k0_));                       \
  pb1 = *(const u4a*)(Bg + (k0_) + a32);
  QKV_FETCH(0)

  for (int k0 = 0; k0 < K; k0 += 64) {
    *(u4a*)(Al)               = pa0;
    *(u4a*)(Al + 32 * GS)     = pa1;
    *(u4a*)(Al + 64 * GS)     = pa2;
    *(u4a*)(Al + 96 * GS)     = pa3;
    *(u4a*)(Bl)               = pb0;
    *(u4a*)(Bl + 32 * GS)     = pb1;
    __syncthreads();
    if (k0 + 64 < K) { QKV_FETCH(k0 + 64) }   // overlaps MFMAs below
#pragma unroll
    for (int ks = 0; ks < 2; ++ks) {
      bf16x8 af[4], bfr[2];
#pragma unroll
      for (int i = 0; i < 4; ++i)
        af[i]  = ld_frag(As + (mw + i * 16 + l16) * GS + ks * 32 + quad * 8);
#pragma unroll
      for (int j = 0; j < 2; ++j)
        bfr[j] = ld_frag(Bs + (nw + j * 16 + l16) * GS + ks * 32 + quad * 8);
#pragma unroll
      for (int i = 0; i < 4; ++i)
#pragma unroll
        for (int j = 0; j < 2; ++j)
          acc[i][j] = __builtin_amdgcn_mfma_f32_16x16x32_bf16(af[i], bfr[j], acc[i][j], 0, 0, 0);
    }
    __syncthreads();
  }
#undef QKV_FETCH
  // C/D layout: col=lane&15 (N), row=quad*4+reg (M)
  if (blockIdx.z < 2) {
    ushort* C = blockIdx.z == 0 ? Qo : Ko;
    const float sc = blockIdx.z == 0 ? 0.125f : 1.0f;  // fold 1/sqrt(dk) into Q
#pragma unroll
    for (int i = 0; i < 4; ++i)
#pragma unroll
      for (int j = 0; j < 2; ++j)
#pragma unroll
        for (int r = 0; r < 4; ++r) {
          int row = m0 + mw + i * 16 + quad * 4 + r;
          int col = n0 + nw + j * 16 + l16;
          C[(size_t)row * N + col] = f2b(acc[i][j][r] * sc);
        }
  } else {
    // Vt[b][h][dv][s] (stride VS): h == blockIdx.y, dv = col&63
#pragma unroll
    for (int i = 0; i < 4; ++i)
#pragma unroll
      for (int j = 0; j < 2; ++j) {
        int col = n0 + nw + j * 16 + l16;
        int h = col >> 6, dv = col & 63;
        int t = m0 + mw + i * 16 + quad * 4;
        int b = t >> 11, s = t & 2047;
        u2a pw;
        pw.x = (uint32_t)f2b(acc[i][j][0]) | ((uint32_t)f2b(acc[i][j][1]) << 16);
        pw.y = (uint32_t)f2b(acc[i][j][2]) | ((uint32_t)f2b(acc[i][j][3]) << 16);
        *(u2a*)(Vt + (((size_t)b * 12 + h) * 64 + dv) * VS + s) = pw;
      }
  }
}

// ---------------------------------------------------------------------------
// Output projection: C[M,N](fp32) = A[M,K](bf16)*B[N,K]^T(bf16).
// BM=BN=64, BK=64, named-scalar double buffer. grid (64,12).
// ---------------------------------------------------------------------------
__global__ __launch_bounds__(256) void gemm_out(
    const ushort* __restrict__ A, const ushort* __restrict__ B,
    float* __restrict__ C, int M, int N, int K)
{
  const int m0 = blockIdx.x * 64, n0 = blockIdx.y * 64;
  __shared__ ushort As[64 * GS];
  __shared__ ushort Bs[64 * GS];
  const int tid = threadIdx.x, wave = tid >> 6, lane = tid & 63;
  const int quad = lane >> 4, l16 = lane & 15;
  const int mw = (wave & 1) * 32, nw = (wave >> 1) * 32;
  const int rr = tid >> 3, cc = (tid & 7) * 8;
  const ushort* Ag = A + (size_t)(m0 + rr) * K + cc;
  const ushort* Bg = B + (size_t)(n0 + rr) * K + cc;
  const size_t a32 = (size_t)32 * K;
  ushort* Al = As + rr * GS + cc;
  ushort* Bl = Bs + rr * GS + cc;
  f32x4 acc[2][2] = {};

  u4a pa0, pa1, pb0, pb1;
#define OUT_FETCH(k0_)                                   \
  pa0 = *(const u4a*)(Ag + (k0_));                       \
  pa1 = *(const u4a*)(Ag + (k0_) + a32);                 \
  pb0 = *(const u4a*)(Bg + (k0_));                       \
  pb1 = *(const u4a*)(Bg + (k0_) + a32);
  OUT_FETCH(0)

  for (int k0 = 0; k0 < K; k0 += 64) {
    *(u4a*)(Al)           = pa0;
    *(u4a*)(Al + 32 * GS) = pa1;
    *(u4a*)(Bl)           = pb0;
    *(u4a*)(Bl + 32 * GS) = pb1;
    __syncthreads();
    if (k0 + 64 < K) { OUT_FETCH(k0 + 64) }
#pragma unroll
    for (int ks = 0; ks < 2; ++ks) {
      bf16x8 af[2], bfr[2];
#pragma unroll
      for (int i = 0; i < 2; ++i)
        af[i]  = ld_frag(As + (mw + i * 16 + l16) * GS + ks * 32 + quad * 8);
#pragma unroll
      for (int j = 0; j < 2; ++j)
        bfr[j] = ld_frag(Bs + (nw + j * 16 + l16) * GS + ks * 32 + quad * 8);
#pragma unroll
      for (int i = 0; i < 2; ++i)
#pragma unroll
        for (int j = 0; j < 2; ++j)
          acc[i][j] = __builtin_amdgcn_mfma_f32_16x16x32_bf16(af[i], bfr[j], acc[i][j], 0, 0, 0);
    }
    __syncthreads();
  }
#undef OUT_FETCH
#pragma unroll
  for (int i = 0; i < 2; ++i)
#pragma unroll
    for (int j = 0; j < 2; ++j)
#pragma unroll
      for (int r = 0; r < 4; ++r) {
        int row = m0 + mw + i * 16 + quad * 4 + r;
        int col = n0 + nw + j * 16 + l16;
        C[(size_t)row * N + col] = acc[i][j][r];
      }
}

// ---------------------------------------------------------------------------
// Causal flash attention, TILE-SHARED strips + K-split + named-scalar
// register prefetch: grid (32,12,2); x = pair*2 + j. Block owns q-tiles
// A=pair, B=31-pair; iterates kt ≡ j (mod 2), staging each K/V tile once for
// both strips; next tile fetched into named VGPRs during compute.
// Q pre-scaled by 1/8. Emits unnormalized partials + (m,l) per strip.
// ---------------------------------------------------------------------------
__global__ __launch_bounds__(256) void attn_kernel(
    const ushort* __restrict__ Qb, const ushort* __restrict__ Kb,
    const ushort* __restrict__ Vt, ushort* __restrict__ Opart,
    float2* __restrict__ MLp)
{
  const int S = 2048, DM = 768;
  const int pair = blockIdx.x >> 1, j = blockIdx.x & 1;
  const int h = blockIdx.y, bb = blockIdx.z;
  const ushort* Qp  = Qb + (size_t)bb * S * DM + h * 64;
  const ushort* Kp  = Kb + (size_t)bb * S * DM + h * 64;
  const ushort* Vth = Vt + ((size_t)bb * 12 + h) * 64 * VS;   // [dv][s]

  __shared__ ushort Ks[128 * 72];     // [kk][dk], pad 64->72
  __shared__ ushort Vs[64 * 136];     // [dv][kk], pad 128->136
  __shared__ ushort Ps[4][16 * 136];  // per-wave P[q][kk], pad 128->136

  const int tid = threadIdx.x, wave = tid >> 6, lane = tid & 63;
  const int quad = lane >> 4, l16 = lane & 15;
  const float LOG2E = 1.44269504f;
  const float NEG_BIG = -1.0e30f;

  const int qtA = pair, qtB = 31 - pair;
  const int qgA = qtA * 64 + wave * 16 + l16;
  const int qgB = qtB * 64 + wave * 16 + l16;
  const int nktA = (qtA >> 1) + 1, nktB = (qtB >> 1) + 1;

  // Q fragments for both strips (B operand of S^T = K*Q^T)
  bf16x8 bqA0 = ld_frag(Qp + (size_t)qgA * DM + quad * 8);
  bf16x8 bqA1 = ld_frag(Qp + (size_t)qgA * DM + 32 + quad * 8);
  bf16x8 bqB0 = ld_frag(Qp + (size_t)qgB * DM + quad * 8);
  bf16x8 bqB1 = ld_frag(Qp + (size_t)qgB * DM + 32 + quad * 8);

  f32x4 accA[4] = {}, accB[4] = {};
  float mA = NEG_BIG, lA = 0.0f, mB = NEG_BIG, lB = 0.0f;

  // K chunk coords: row kr_ = tid>>3 (+32i), col kc_ = (tid&7)*8
  // V chunk coords: row vrow = tid>>4 (+16i), col vc_ = (tid&15)*8
  const int krr = tid >> 3, kcc = (tid & 7) * 8;
  const int vrr = tid >> 4, vcc = (tid & 15) * 8;
  const ushort* Kg = Kp + (size_t)krr * DM + kcc;
  const size_t k32 = (size_t)32 * DM;
  const ushort* Vg = Vth + (size_t)vrr * VS + vcc;
  const size_t v16 = (size_t)16 * VS;
  ushort* Kl = Ks + krr * 72 + kcc;
  ushort* Vl = Vs + vrr * 136 + vcc;

  u4a kr0, kr1, kr2, kr3, vr0, vr1, vr2, vr3;
#define ATTN_FETCH(kt_) {                                        \
  const size_t o = (size_t)(kt_) * 128;                          \
  kr0 = *(const u4a*)(Kg + o * DM);                              \
  kr1 = *(const u4a*)(Kg + o * DM + k32);                        \
  kr2 = *(const u4a*)(Kg + o * DM + 2 * k32);                    \
  kr3 = *(const u4a*)(Kg + o * DM + 3 * k32);                    \
  vr0 = *(const u4a*)(Vg + o);                                   \
  vr1 = *(const u4a*)(Vg + o + v16);                             \
  vr2 = *(const u4a*)(Vg + o + 2 * v16);                         \
  vr3 = *(const u4a*)(Vg + o + 3 * v16); }
  ATTN_FETCH(j)

  for (int kt = j; kt < nktB; kt += 2) {
    const int kk0 = kt * 128;
    *(u4a*)(Kl)            = kr0;
    *(u4a*)(Kl + 32 * 72)  = kr1;
    *(u4a*)(Kl + 64 * 72)  = kr2;
    *(u4a*)(Kl + 96 * 72)  = kr3;
    *(u4a*)(Vl)            = vr0;
    *(u4a*)(Vl + 16 * 136) = vr1;
    *(u4a*)(Vl + 32 * 136) = vr2;
    *(u4a*)(Vl + 48 * 136) = vr3;
    __syncthreads();
    if (kt + 2 < nktB) ATTN_FETCH(kt + 2)   // overlaps compute below

    // ---- compute one strip from the staged tile ----
    auto strip = [&](const bf16x8& bq0, const bf16x8& bq1, f32x4* acc_o,
                     float& m_run, float& l_run, int qg, int nkt) {
      f32x4 sacc[8] = {};
#pragma unroll
      for (int tt = 0; tt < 8; ++tt) {
        bf16x8 ak0 = ld_frag(Ks + (tt * 16 + l16) * 72 + quad * 8);
        bf16x8 ak1 = ld_frag(Ks + (tt * 16 + l16) * 72 + 32 + quad * 8);
        sacc[tt] = __builtin_amdgcn_mfma_f32_16x16x32_bf16(ak0, bq0, sacc[tt], 0, 0, 0);
        sacc[tt] = __builtin_amdgcn_mfma_f32_16x16x32_bf16(ak1, bq1, sacc[tt], 0, 0, 0);
      }
      const bool domask = (kt == nkt - 1);
      float mt = NEG_BIG;
#pragma unroll
      for (int tt = 0; tt < 8; ++tt)
#pragma unroll
        for (int r = 0; r < 4; ++r) {
          float s = sacc[tt][r];
          if (domask) {
            int kkg = kk0 + tt * 16 + quad * 4 + r;
            if (kkg > qg) s = NEG_BIG;
          }
          sacc[tt][r] = s;
          mt = fmaxf(mt, s);
        }
      mt = fmaxf(mt, __shfl_xor(mt, 16, 64));
      mt = fmaxf(mt, __shfl_xor(mt, 32, 64));
      float mnew = fmaxf(m_run, mt);
      float alpha = exp2f((m_run - mnew) * LOG2E);
      float lsum = 0.0f;
#pragma unroll
      for (int tt = 0; tt < 8; ++tt) {
        float p0 = exp2f((sacc[tt][0] - mnew) * LOG2E);
        float p1 = exp2f((sacc[tt][1] - mnew) * LOG2E);
        float p2 = exp2f((sacc[tt][2] - mnew) * LOG2E);
        float p3 = exp2f((sacc[tt][3] - mnew) * LOG2E);
        lsum += (p0 + p1) + (p2 + p3);
        // truncation pack (P in [0,1]: <=2^-8 rel err)
        uint32_t u0 = __builtin_bit_cast(uint32_t, p0);
        uint32_t u1 = __builtin_bit_cast(uint32_t, p1);
        uint32_t u2 = __builtin_bit_cast(uint32_t, p2);
        uint32_t u3 = __builtin_bit_cast(uint32_t, p3);
        u2a pw;
        pw.x = (u0 >> 16) | (u1 & 0xFFFF0000u);
        pw.y = (u2 >> 16) | (u3 & 0xFFFF0000u);
        *(u2a*)(&Ps[wave][l16 * 136 + tt * 16 + quad * 4]) = pw;
      }
      asm volatile("s_waitcnt lgkmcnt(0)" ::: "memory");
      lsum += __shfl_xor(lsum, 16, 64);
      lsum += __shfl_xor(lsum, 32, 64);
      l_run = l_run * alpha + lsum;
      m_run = mnew;
      float ar0 = __shfl(alpha, quad * 4 + 0, 64);
      float ar1 = __shfl(alpha, quad * 4 + 1, 64);
      float ar2 = __shfl(alpha, quad * 4 + 2, 64);
      float ar3 = __shfl(alpha, quad * 4 + 3, 64);
#pragma unroll
      for (int ct = 0; ct < 4; ++ct) {
        acc_o[ct][0] *= ar0; acc_o[ct][1] *= ar1;
        acc_o[ct][2] *= ar2; acc_o[ct][3] *= ar3;
      }
#pragma unroll
      for (int ks = 0; ks < 4; ++ks) {
        bf16x8 ap = ld_frag(&Ps[wave][l16 * 136 + ks * 32 + quad * 8]);
#pragma unroll
        for (int ct = 0; ct < 4; ++ct) {
          bf16x8 bv = ld_frag(Vs + (size_t)(ct * 16 + l16) * 136 + ks * 32 + quad * 8);
          acc_o[ct] = __builtin_amdgcn_mfma_f32_16x16x32_bf16(ap, bv, acc_o[ct], 0, 0, 0);
        }
      }
    };

    strip(bqB0, bqB1, accB, mB, lB, qgB, nktB);       // always active
    if (kt < nktA)
      strip(bqA0, bqA1, accA, mA, lA, qgA, nktA);     // block-uniform branch
    __syncthreads();   // protect Ks/Vs before next restage
  }
#undef ATTN_FETCH

  // store unnormalized partials (bf16 O + per-row m,l) for both strips
  const int base = ((bb * 12 + h) << 5);
  const int r0 = wave * 16 + quad * 4;
  {
    const int slot = (base + qtB) * 2 + j;
    ushort* Os = Opart + (size_t)slot * 4096;
#pragma unroll
    for (int ct = 0; ct < 4; ++ct) {
      int col = ct * 16 + l16;
      Os[(r0 + 0) * 64 + col] = f2b(accB[ct][0]);
      Os[(r0 + 1) * 64 + col] = f2b(accB[ct][1]);
      Os[(r0 + 2) * 64 + col] = f2b(accB[ct][2]);
      Os[(r0 + 3) * 64 + col] = f2b(accB[ct][3]);
    }
    if (quad == 0)
      MLp[(size_t)slot * 64 + wave * 16 + l16] = make_float2(mB, lB);
  }
  {
    const int slot = (base + qtA) * 2 + j;
    ushort* Os = Opart + (size_t)slot * 4096;
#pragma unroll
    for (int ct = 0; ct < 4; ++ct) {
      int col = ct * 16 + l16;
      Os[(r0 + 0) * 64 + col] = f2b(accA[ct][0]);
      Os[(r0 + 1) * 64 + col] = f2b(accA[ct][1]);
      Os[(r0 + 2) * 64 + col] = f2b(accA[ct][2]);
      Os[(r0 + 3) * 64 + col] = f2b(accA[ct][3]);
    }
    if (quad == 0)
      MLp[(size_t)slot * 64 + wave * 16 + l16] = make_float2(mA, lA);
  }
}

// ---------------------------------------------------------------------------
// Combine the two K-parity partials per strip -> Abuf (b, s, h*64) bf16.
// grid 768, 256 threads, 16 elems/thread. Empty partial: m=-1e30 -> weight 0.
// ---------------------------------------------------------------------------
__global__ __launch_bounds__(256) void combine_kernel(
    const ushort* __restrict__ Opart, const float2* __restrict__ MLp,
    ushort* __restrict__ Ab)
{
  const int sid = blockIdx.x;
  const int bb = sid / 384, rem = sid % 384, h = rem >> 5, qt = rem & 31;
  const int t = threadIdx.x, row = t >> 2, cg = (t & 3) * 16;
  float2 ml0 = MLp[(size_t)(sid * 2) * 64 + row];
  float2 ml1 = MLp[(size_t)(sid * 2 + 1) * 64 + row];
  float ms = fmaxf(ml0.x, ml1.x);
  float w0 = exp2f((ml0.x - ms) * 1.44269504f);
  float w1 = exp2f((ml1.x - ms) * 1.44269504f);
  float inv = 1.0f / (ml0.y * w0 + ml1.y * w1);
  w0 *= inv; w1 *= inv;
  const ushort* p0 = Opart + (size_t)(sid * 2) * 4096 + row * 64 + cg;
  ushort* dst = Ab + ((size_t)(bb * 2048 + qt * 64 + row)) * 768 + h * 64 + cg;
#pragma unroll
  for (int g = 0; g < 2; ++g) {
    u4a a = *(const u4a*)(p0 + g * 8);
    u4a b = *(const u4a*)(p0 + 4096 + g * 8);
    u4a o;
    o.x = comb2(a.x, b.x, w0, w1);
    o.y = comb2(a.y, b.y, w0, w1);
    o.z = comb2(a.z, b.z, w0, w1);
    o.w = comb2(a.w, b.w, w0, w1);
    *(u4a*)(dst + g * 8) = o;
  }
}

// ---------------------------------------------------------------------------
extern "C" void kernel_launch(void* const* d_in, const int* in_sizes, int n_in,
                              void* d_out, int out_size, void* d_ws, size_t ws_size,
                              hipStream_t stream) {
  (void)in_sizes; (void)n_in; (void)out_size; (void)ws_size;
  const float* x  = (const float*)d_in[0];
  const float* wq = (const float*)d_in[1];
  const float* wk = (const float*)d_in[2];
  const float* wv = (const float*)d_in[3];
  const float* wo = (const float*)d_in[4];

  const size_t NT = (size_t)4096 * 768;   // tokens x d_model
  const size_t NW = (size_t)768 * 768;
  const size_t NV = (size_t)24 * 64 * VS; // padded Vt
  ushort* xb    = (ushort*)d_ws;          // reused as Abuf after QKV GEMM
  ushort* Qbuf  = xb + NT;
  ushort* Kbuf  = Qbuf + NT;
  ushort* Vt    = Kbuf + NT;              // (b, h, dv, s) stride VS
  ushort* wqb   = Vt + NV;
  ushort* wkb   = wqb + NW;
  ushort* wvb   = wkb + NW;
  ushort* wob   = wvb + NW;
  ushort* Opart = wob + NW;               // 1536 x 64 x 64 bf16
  float2* MLp   = (float2*)(Opart + (size_t)1536 * 4096);  // 1536 x 64
  ushort* Abuf  = xb;                     // lifetime-disjoint reuse

  // fp32 -> bf16 (x + all weights)
  convert_kernel<<<2688, 256, 0, stream>>>(x, wq, wk, wv, wo,
                                           xb, wqb, wkb, wvb, wob);
  // Q/K/V projections (Q pre-scaled; V lands transposed in Vt)
  gemm_qkv<<<dim3(32, 12, 3), 256, 0, stream>>>(
      xb, wqb, wkb, wvb, Qbuf, Kbuf, Vt, 4096, 768, 768);
  // causal flash attention: shared-tile strips, 768 uniform sub-blocks
  attn_kernel<<<dim3(32, 12, 2), 256, 0, stream>>>(Qbuf, Kbuf, Vt, Opart, MLp);
  // merge partials -> Abuf
  combine_kernel<<<768, 256, 0, stream>>>(Opart, MLp, Abuf);
  // output projection (fp32 out)
  gemm_out<<<dim3(64, 12), 256, 0, stream>>>(
      Abuf, wob, (float*)d_out, 4096, 768, 768);
}